// Round 2
// baseline (752.885 us; speedup 1.0000x reference)
//
#include <hip/hip_runtime.h>
#include <stdint.h>

// ============================================================================
// SubspaceRankHopLayer on MI355X (gfx950)
//
// R3: k_biggemm pure-DMA GEMM w/ chunk-padded LDS (verified 728.9 us).
// R5 (this round): counters showed only harness fills (1GiB @160us) -> every
// kernel <160us; model says sum ~250us vs 730 measured => serialization +
// launch gaps + tiny-grid latency kernels idle the chip. Fix by fusion:
//   - k_pre: gramchol (blocks 0-4) || L->bf16 stream (blocks 5+). Dropped Ul
//     LDS stage (gram reads U from L2) so LDS=17KB keeps stream occupancy.
//   - chol64: div-free masked update sweep (was runtime e/rem int div).
//   - k_post: hwT || t2w || wbf (896 blocks, role-ranged).
//   - k_gg:   biggemm || gradgemm (768 blocks, shared LDS arena).
//   - k_finln: fingemm + LayerNorm epilogue (kills Hpre 16MB roundtrip).
// 15 -> 10 launches. Predict 730 -> ~600us.
// ============================================================================

typedef __attribute__((ext_vector_type(8))) short  s16x8;   // 8 bf16 (4 VGPR)
typedef __attribute__((ext_vector_type(4))) float  f32x4;

#define NNODE 8192
#define DIN   256
#define KHOP  5
#define SDM   64

// ---------------- ws layout (bytes) ----------------
static const size_t OFF_Q    = 0;                                   // Q f32 [5][256][64]
static const size_t OFF_QT   = OFF_Q   + (size_t)5*256*64*4;        // Qt bf16 [5][64][256]
static const size_t OFF_ZT   = OFF_QT  + (size_t)5*64*256*2;        // Zt bf16 [5][8192][64]
static const size_t OFF_GP   = OFF_ZT  + (size_t)5*8192*64*2;       // Gpart f32 [5][16][64][64]
static const size_t OFF_LM   = OFF_GP  + (size_t)5*16*4096*4;       // Lm f32 [5][64][64]
static const size_t OFF_RD   = OFF_LM  + (size_t)5*4096*4;          // rdiag f32 [5][64]
static const size_t OFF_LU   = OFF_RD  + (size_t)5*64*4;            // Lu f32 [5][64][64]
static const size_t OFF_RDU  = OFF_LU  + (size_t)5*4096*4;          // rdiag_u f32 [5][64]
static const size_t OFF_RE   = OFF_RDU + (size_t)5*64*4;            // rank_eff [5] (pad 64)
static const size_t OFF_W    = OFF_RE  + 64;                        // w [5] (pad 64)
static const size_t OFF_T2   = OFF_W   + 64;                        // T2w bf16 [5][256][64]
static const size_t OFF_HWT  = OFF_T2  + (size_t)5*256*64*2;        // hwT bf16 [256][8192]
static const size_t OFF_WBF  = OFF_HWT + (size_t)256*8192*2;        // W_in bf16 [256][256]
static const size_t OFF_HP   = OFF_WBF + (size_t)256*256*2;         // Hprox bf16 [8192][256]
static const size_t OFF_PART = OFF_HP  + (size_t)8192*256*2;        // partial bf16 [9][8192][256]
static const size_t OFF_LBF  = OFF_PART + (size_t)9*8192*256*2;     // L bf16 [8192][8192] (128 MB)

__device__ __forceinline__ unsigned short f2bf(float f){
  unsigned u = __builtin_bit_cast(unsigned, f);
  u += 0x7FFFu + ((u >> 16) & 1u);            // RNE
  return (unsigned short)(u >> 16);
}
__device__ __forceinline__ float bf2f(unsigned h){
  return __builtin_bit_cast(float, h << 16);
}
__device__ __forceinline__ void gl_lds16(const void* g, void* l){
  __builtin_amdgcn_global_load_lds(
      (const __attribute__((address_space(1))) void*)g,
      (__attribute__((address_space(3))) void*)l, 16, 0, 0);
}
__device__ __forceinline__ f32x4 mfma16(s16x8 a, s16x8 b, f32x4 c){
  return __builtin_amdgcn_mfma_f32_16x16x32_bf16(a, b, c, 0, 0, 0);
}

// in-place Cholesky of 64x64 SPD in LDS (pitch 65); rd = 1/diag. 256 threads.
// R5: div-free masked update sweep (each (i,l) written by exactly one thread
// -> bitwise identical to the old rem-div mapping).
__device__ void chol64(float* A, float* rd, int tid){
  #pragma unroll 1
  for (int j = 0; j < 64; ++j){
    if (tid == 0){
      float d = sqrtf(fmaxf(A[j*65+j], 1e-20f));
      A[j*65+j] = d; rd[j] = 1.0f / d;
    }
    __syncthreads();
    float rinv = rd[j];
    for (int i = j+1+tid; i < 64; i += 256) A[i*65+j] *= rinv;
    __syncthreads();
    #pragma unroll 1
    for (int e = tid; e < 4096; e += 256){
      int i = e >> 6, l = e & 63;
      if (i > j && l > j && l <= i) A[i*65+l] -= A[i*65+j] * A[l*65+j];
    }
    __syncthreads();
  }
}

// ---------------------------------------------------------------------------
// K_PRE: blocks 0-4: Gram+Cholesky of U_k (reads U from L2, no Ul stage).
//        blocks 5..32772: L f32 -> bf16 streaming cvt.
// Chol blocks dispatch first so they overlap the whole stream phase.
// ---------------------------------------------------------------------------
__global__ __launch_bounds__(256) void k_pre(const float* __restrict__ U,
                                             const float* __restrict__ L,
                                             float* __restrict__ Lu,
                                             float* __restrict__ rdu,
                                             unsigned short* __restrict__ Lbf){
  __shared__ float A[64*65];
  __shared__ float rd[64];
  int tid = threadIdx.x;
  if (blockIdx.x >= 5){
    size_t e = ((size_t)(blockIdx.x-5)*256 + tid)*8;
    f32x4 a = *(const f32x4*)(L + e);
    f32x4 b = *(const f32x4*)(L + e + 4);
    uint4 u;
    u.x = (unsigned)f2bf(a[0]) | ((unsigned)f2bf(a[1]) << 16);
    u.y = (unsigned)f2bf(a[2]) | ((unsigned)f2bf(a[3]) << 16);
    u.z = (unsigned)f2bf(b[0]) | ((unsigned)f2bf(b[1]) << 16);
    u.w = (unsigned)f2bf(b[2]) | ((unsigned)f2bf(b[3]) << 16);
    *(uint4*)(Lbf + e) = u;
    return;
  }
  int k = blockIdx.x;
  const float* Uk = U + (size_t)k*16384;
  int ti = tid >> 4, tj = tid & 15;
  float s[16];
  #pragma unroll
  for (int i = 0; i < 16; ++i) s[i] = 0.0f;
  for (int n = 0; n < 256; ++n){
    f32x4 xa = *(const f32x4*)(Uk + n*64 + ti*4);
    f32x4 xb = *(const f32x4*)(Uk + n*64 + tj*4);
    #pragma unroll
    for (int p = 0; p < 4; ++p)
      #pragma unroll
      for (int q = 0; q < 4; ++q) s[p*4+q] += xa[p]*xb[q];
  }
  #pragma unroll
  for (int p = 0; p < 4; ++p)
    #pragma unroll
    for (int q = 0; q < 4; ++q) A[(ti*4+p)*65 + tj*4+q] = s[p*4+q];
  __syncthreads();
  chol64(A, rd, tid);
  for (int e = tid; e < 4096; e += 256) Lu[(size_t)k*4096 + e] = A[(e>>6)*65 + (e&63)];
  if (tid < 64) rdu[k*64 + tid] = rd[tid];
}

// ---------------------------------------------------------------------------
// K1b: wave-parallel forward solve L x = u_row -> Q rows. grid(64,5).
// ---------------------------------------------------------------------------
__global__ __launch_bounds__(256) void k_qsolve(const float* __restrict__ U,
                                                const float* __restrict__ Lu,
                                                const float* __restrict__ rdu,
                                                float* __restrict__ Qf,
                                                unsigned short* __restrict__ Qt){
  int k = blockIdx.y, tid = threadIdx.x, wave = tid >> 6, lane = tid & 63;
  __shared__ float Al[64*65];
  __shared__ float rds[64];
  for (int e = tid; e < 4096; e += 256) Al[(e>>6)*65 + (e&63)] = Lu[(size_t)k*4096 + e];
  if (tid < 64) rds[tid] = rdu[k*64 + tid];
  __syncthreads();
  int n = blockIdx.x*4 + wave;
  float x = U[((size_t)k*256 + n)*64 + lane];
  #pragma unroll
  for (int j = 0; j < 64; ++j){
    float zj = __shfl(x, j) * rds[j];
    x = (lane == j) ? zj : (lane > j ? x - Al[lane*65+j]*zj : x);
  }
  Qf[((size_t)k*256 + n)*64 + lane] = x;
  Qt[(size_t)k*16384 + lane*256 + n] = f2bf(x);   // Qt[k][s][d]
}

// ---------------------------------------------------------------------------
// K2: Z_k = hops_k @ Q_k  [8192,64] bf16.  grid(64,5), BM=128 BN=64 BK=64.
// ---------------------------------------------------------------------------
__global__ __launch_bounds__(256,2) void k_zgemm(const float* __restrict__ hops,
                                                 const unsigned short* __restrict__ Qt,
                                                 unsigned short* __restrict__ Zt){
  __shared__ __align__(16) unsigned short Al[128][72];
  __shared__ __align__(16) unsigned short Bl[64][64];
  int tid = threadIdx.x, lane = tid & 63, wave = tid >> 6;
  int q = lane >> 4, r = lane & 15;
  int k = blockIdx.y, m0 = blockIdx.x * 128;
  f32x4 acc[2][4];
  #pragma unroll
  for (int a = 0; a < 2; ++a)
    #pragma unroll
    for (int b = 0; b < 4; ++b) acc[a][b] = (f32x4){0,0,0,0};
  int rr = tid >> 1, half = tid & 1;
  for (int it = 0; it < 4; ++it){
    __syncthreads();
    #pragma unroll
    for (int i = 0; i < 2; ++i){
      int o = i*4096 + wave*1024 + lane*16;
      int srow = o >> 7, kc = (o & 127) >> 1;
      gl_lds16(Qt + (size_t)k*16384 + srow*256 + it*64 + kc,
               (char*)&Bl[0][0] + i*4096 + wave*1024);
    }
    const float* ga = hops + ((size_t)k*NNODE + m0 + rr)*256 + it*64 + half*32;
    f32x4 v[8];
    #pragma unroll
    for (int i = 0; i < 8; ++i) v[i] = *(const f32x4*)(ga + i*4);
    #pragma unroll
    for (int i = 0; i < 4; ++i){
      s16x8 t;
      #pragma unroll
      for (int j = 0; j < 8; ++j){ int e = i*8+j; t[j] = (short)f2bf(v[e>>2][e&3]); }
      *(s16x8*)&Al[rr][half*32 + i*8] = t;
    }
    __syncthreads();
    #pragma unroll
    for (int h = 0; h < 2; ++h){
      int ko = h*32 + q*8;
      s16x8 b[4];
      #pragma unroll
      for (int ni = 0; ni < 4; ++ni) b[ni] = *(const s16x8*)&Bl[ni*16 + r][ko];
      #pragma unroll
      for (int mi = 0; mi < 2; ++mi){
        s16x8 a = *(const s16x8*)&Al[wave*32 + mi*16 + r][ko];
        #pragma unroll
        for (int ni = 0; ni < 4; ++ni) acc[mi][ni] = mfma16(a, b[ni], acc[mi][ni]);
      }
    }
  }
  #pragma unroll
  for (int mi = 0; mi < 2; ++mi)
    #pragma unroll
    for (int ni = 0; ni < 4; ++ni)
      #pragma unroll
      for (int ii = 0; ii < 4; ++ii){
        int m = m0 + wave*32 + mi*16 + q*4 + ii;
        int sc = ni*16 + r;
        Zt[((size_t)k*NNODE + m)*64 + sc] = f2bf(acc[mi][ni][ii]);
      }
}

// ---------------------------------------------------------------------------
// K3: partial Gram over 512-row chunks. grid(5,16).
// ---------------------------------------------------------------------------
__global__ __launch_bounds__(256) void k_gpart(const unsigned short* __restrict__ Zt,
                                               float* __restrict__ Gp){
  int k = blockIdx.x, c = blockIdx.y, tid = threadIdx.x;
  __shared__ __align__(16) unsigned short Zl[128][64];
  int ti = tid >> 4, tj = tid & 15;
  float acc[16];
  #pragma unroll
  for (int i = 0; i < 16; ++i) acc[i] = 0.0f;
  for (int sub = 0; sub < 4; ++sub){
    const char* gb = (const char*)Zt + ((size_t)k*NNODE + c*512 + sub*128)*128;
    __syncthreads();
    #pragma unroll
    for (int i = 0; i < 4; ++i){
      int o = i*4096 + tid*16;
      *(uint4*)((char*)&Zl[0][0] + o) = *(const uint4*)(gb + o);
    }
    __syncthreads();
    for (int n = 0; n < 128; ++n){
      const unsigned short* row = &Zl[n][0];
      uint2 ua = *(const uint2*)(row + ti*4);
      uint2 ub = *(const uint2*)(row + tj*4);
      float xa[4] = { bf2f(ua.x & 0xffff), bf2f(ua.x >> 16), bf2f(ua.y & 0xffff), bf2f(ua.y >> 16) };
      float xb[4] = { bf2f(ub.x & 0xffff), bf2f(ub.x >> 16), bf2f(ub.y & 0xffff), bf2f(ub.y >> 16) };
      #pragma unroll
      for (int p = 0; p < 4; ++p)
        #pragma unroll
        for (int qn = 0; qn < 4; ++qn) acc[p*4+qn] += xa[p]*xb[qn];
    }
  }
  float* o = Gp + ((size_t)k*16 + c)*4096;
  #pragma unroll
  for (int p = 0; p < 4; ++p)
    #pragma unroll
    for (int qn = 0; qn < 4; ++qn) o[(ti*4+p)*64 + tj*4+qn] = acc[p*4+qn];
}

// ---------------------------------------------------------------------------
// K4: reduce Gpart -> G; rank_eff; M = I + coeff*G; chol(M). 5 blocks.
// ---------------------------------------------------------------------------
__global__ __launch_bounds__(256) void k_gred(const float* __restrict__ Gp,
                                              float* __restrict__ LmO,
                                              float* __restrict__ rdO,
                                              float* __restrict__ reO){
  int k = blockIdx.x, tid = threadIdx.x;
  __shared__ float A[64*65];
  __shared__ float rd[64];
  __shared__ float red[256];
  int ti = tid >> 4, tj = tid & 15;
  float s[16];
  #pragma unroll
  for (int i = 0; i < 16; ++i) s[i] = 0.0f;
  for (int c = 0; c < 16; ++c){
    const float* g = Gp + ((size_t)k*16 + c)*4096 + (ti*4)*64 + tj*4;
    #pragma unroll
    for (int p = 0; p < 4; ++p)
      #pragma unroll
      for (int qn = 0; qn < 4; ++qn) s[p*4+qn] += g[p*64+qn];
  }
  const float sc    = 1.0f / (8192.0f + 1e-8f);
  const float coeff = 64.0f / (8192.0f*0.25f + 1e-8f);
  float trp = 0.0f, tr2p = 0.0f;
  #pragma unroll
  for (int p = 0; p < 4; ++p)
    #pragma unroll
    for (int qn = 0; qn < 4; ++qn){
      float gg = s[p*4+qn];
      float sg = gg * sc;
      tr2p += sg*sg;
      int row = ti*4+p, col = tj*4+qn;
      if (row == col) trp += sg;
      A[row*65 + col] = (row == col ? 1.0f : 0.0f) + coeff*gg;
    }
  red[tid] = trp; __syncthreads();
  for (int o = 128; o > 0; o >>= 1){ if (tid < o) red[tid] += red[tid+o]; __syncthreads(); }
  float tr = red[0]; __syncthreads();
  red[tid] = tr2p; __syncthreads();
  for (int o = 128; o > 0; o >>= 1){ if (tid < o) red[tid] += red[tid+o]; __syncthreads(); }
  float tr2 = red[0]; __syncthreads();
  if (tid == 0) reO[k] = tr*tr / (tr2 + 1e-8f);
  chol64(A, rd, tid);
  for (int e = tid; e < 4096; e += 256) LmO[(size_t)k*4096 + e] = A[(e>>6)*65 + (e&63)];
  if (tid < 64) rdO[k*64 + tid] = rd[tid];
}

// ---------------------------------------------------------------------------
// K5: tau, softmax over rank_effs -> w; write output tail. 1 block.
// ---------------------------------------------------------------------------
__global__ void k_soft(const float* __restrict__ re, const float* __restrict__ ltau,
                       float* __restrict__ wv, float* __restrict__ dtail){
  if (threadIdx.x == 0){
    float tau = expf(ltau[0]);
    tau = fminf(fmaxf(tau, 0.1f), 10.0f);
    float r[5], m = -1e30f;
    for (int i = 0; i < 5; ++i){ r[i] = re[i]; m = fmaxf(m, r[i]); }
    float e[5], sum = 0.0f;
    for (int i = 0; i < 5; ++i){ e[i] = expf((r[i]-m)/tau); sum += e[i]; }
    for (int i = 0; i < 5; ++i){
      float w = e[i]/sum;
      wv[i] = w; dtail[i] = r[i]; dtail[5+i] = w;
    }
  }
}

// ---------------------------------------------------------------------------
// K_POST: horizontal fusion, 896 blocks:
//   [0,512):   hwT role  (x = i&127 -> n0, y = i>>7 -> d0)
//   [512,832): t2w role  (i-512: k = i>>6, xb = i&63)
//   [832,896): wbf role
// ---------------------------------------------------------------------------
__global__ __launch_bounds__(256) void k_post(const float* __restrict__ hops,
                                              const float* __restrict__ wv,
                                              unsigned short* __restrict__ hwT,
                                              const float* __restrict__ Qf,
                                              const float* __restrict__ LmI,
                                              const float* __restrict__ rdI,
                                              unsigned short* __restrict__ T2w,
                                              const float* __restrict__ Win,
                                              unsigned short* __restrict__ Wbf){
  __shared__ float T[64*65];
  __shared__ float rds[64];
  int bid = blockIdx.x, tid = threadIdx.x;
  if (bid < 512){
    // ---- hwT role ----
    int n0 = (bid & 127)*64, d0 = (bid >> 7)*64;
    float wl[5];
    #pragma unroll
    for (int k = 0; k < 5; ++k) wl[k] = -0.15f * wv[k];   // -ETA*LAM_LAP*w_k
    for (int e = tid; e < 1024; e += 256){
      int row = e >> 4, c4 = (e & 15)*4;
      f32x4 acc = (f32x4){0,0,0,0};
      #pragma unroll
      for (int k = 0; k < 5; ++k){
        f32x4 v = *(const f32x4*)(hops + ((size_t)k*NNODE + n0 + row)*256 + d0 + c4);
        acc += v * wl[k];
      }
      T[row*65 + c4+0] = acc[0]; T[row*65 + c4+1] = acc[1];
      T[row*65 + c4+2] = acc[2]; T[row*65 + c4+3] = acc[3];
    }
    __syncthreads();
    for (int e = tid; e < 1024; e += 256){
      int dr = e >> 4, c4 = (e & 15)*4;
      unsigned short h0 = f2bf(T[(c4+0)*65 + dr]);
      unsigned short h1 = f2bf(T[(c4+1)*65 + dr]);
      unsigned short h2 = f2bf(T[(c4+2)*65 + dr]);
      unsigned short h3 = f2bf(T[(c4+3)*65 + dr]);
      uint2 u; u.x = (unsigned)h0 | ((unsigned)h1 << 16); u.y = (unsigned)h2 | ((unsigned)h3 << 16);
      *(uint2*)(hwT + (size_t)(d0+dr)*NNODE + n0 + c4) = u;
    }
  } else if (bid < 832){
    // ---- t2w role: fwd+bwd solve, T2w = ETA*w_k*(M^-1 Q^T) ----
    int i = bid - 512;
    int k = i >> 6, xb = i & 63;
    int wave = tid >> 6, lane = tid & 63;
    for (int e = tid; e < 4096; e += 256) T[(e>>6)*65 + (e&63)] = LmI[(size_t)k*4096 + e];
    if (tid < 64) rds[tid] = rdI[k*64 + tid];
    __syncthreads();
    int n = xb*4 + wave;
    float x = Qf[((size_t)k*256 + n)*64 + lane];
    #pragma unroll
    for (int j = 0; j < 64; ++j){                 // forward: L z = q
      float zj = __shfl(x, j) * rds[j];
      x = (lane == j) ? zj : (lane > j ? x - T[lane*65+j]*zj : x);
    }
    #pragma unroll
    for (int j = 63; j >= 0; --j){                // backward: L^T y = z
      float yj = __shfl(x, j) * rds[j];
      x = (lane == j) ? yj : (lane < j ? x - T[j*65+lane]*yj : x);
    }
    float scale = 0.5f * wv[k];                   // ETA * w_k
    T2w[((size_t)k*256 + n)*64 + lane] = f2bf(scale * x);
  } else {
    // ---- wbf role ----
    int i = bid - 832;
    int e = (i*256 + tid)*4;
    f32x4 v = *(const f32x4*)(Win + e);
    uint2 u;
    u.x = (unsigned)f2bf(v[0]) | ((unsigned)f2bf(v[1]) << 16);
    u.y = (unsigned)f2bf(v[2]) | ((unsigned)f2bf(v[3]) << 16);
    *(uint2*)(Wbf + e) = u;
  }
}

// ---------------------------------------------------------------------------
// K_GG: horizontal fusion, 768 blocks, shared 49.9 KB LDS arena:
//   [0,512):   biggemm role (bx = i&63, by = i>>6), chunk-padded pure-DMA
//   [512,768): gradgemm role (m0 = (i-512)*32)
// ---------------------------------------------------------------------------
__global__ __launch_bounds__(256,2) void k_gg(const unsigned short* __restrict__ Lbf,
                                              const unsigned short* __restrict__ Bt,
                                              unsigned short* __restrict__ part,
                                              const unsigned short* __restrict__ Zt,
                                              const unsigned short* __restrict__ T2w){
  __shared__ __align__(16) unsigned short SM[24960];   // 49,920 B arena
  int bid = blockIdx.x, tid = threadIdx.x;
  int lane = tid & 63, wave = tid >> 6;
  int q = lane >> 4, r = lane & 15;
  if (bid < 512){
    // ---- biggemm role ----
    unsigned short* Al = SM;            // 16 chunks x 1040 B
    unsigned short* Bl = SM + 16*520;   // 32 chunks x 1040 B
    int m0 = (bid & 63) * 128;
    int by = bid >> 6;
    size_t kbase = (size_t)by * 1024;
    int sr = lane >> 3, sc8 = (lane & 7) * 8;
    f32x4 acc[8][4];
    #pragma unroll
    for (int a = 0; a < 8; ++a)
      #pragma unroll
      for (int b = 0; b < 4; ++b) acc[a][b] = (f32x4){0,0,0,0};
    for (int it = 0; it < 16; ++it){
      size_t k0 = kbase + it*64;
      __syncthreads();
      #pragma unroll
      for (int i = 0; i < 12; ++i){             // 48 chunks: 16 A + 32 B
        int c = i*4 + wave;                     // wave-uniform
        if (c < 16){
          gl_lds16(Lbf + (size_t)(m0 + c*8 + sr)*NNODE + k0 + sc8,
                   (char*)Al + c*1040 + lane*16);
        } else {
          int cb = c - 16;
          gl_lds16(Bt + (size_t)(cb*8 + sr)*NNODE + k0 + sc8,
                   (char*)Bl + cb*1040 + lane*16);
        }
      }
      __syncthreads();
      #pragma unroll
      for (int h = 0; h < 2; ++h){
        int ko = h*32 + q*8;
        s16x8 b[4];
        #pragma unroll
        for (int ni = 0; ni < 4; ++ni){
          int d = wave*64 + ni*16 + r;
          b[ni] = *(const s16x8*)(Bl + (d>>3)*520 + (d&7)*64 + ko);
        }
        #pragma unroll
        for (int mi = 0; mi < 8; ++mi){
          int m = mi*16 + r;
          s16x8 a = *(const s16x8*)(Al + (m>>3)*520 + (m&7)*64 + ko);
          #pragma unroll
          for (int ni = 0; ni < 4; ++ni) acc[mi][ni] = mfma16(a, b[ni], acc[mi][ni]);
        }
      }
    }
    unsigned short* o = part + (size_t)by * 2097152;
    #pragma unroll
    for (int mi = 0; mi < 8; ++mi)
      #pragma unroll
      for (int ni = 0; ni < 4; ++ni)
        #pragma unroll
        for (int ii = 0; ii < 4; ++ii){
          int m = m0 + mi*16 + q*4 + ii;
          int n = wave*64 + ni*16 + r;
          o[(size_t)m*256 + n] = f2bf(acc[mi][ni][ii]);
        }
  } else {
    // ---- gradgemm role: Zstack[8192,320] @ T2w-stack[320,256] -> slab 8 ----
    unsigned short* Al = SM;            // 32 x 64
    unsigned short* Bl = SM + 2048;     // 256 x 64
    int m0 = (bid - 512) * 32;
    f32x4 acc[2][4];
    #pragma unroll
    for (int a = 0; a < 2; ++a)
      #pragma unroll
      for (int b = 0; b < 4; ++b) acc[a][b] = (f32x4){0,0,0,0};
    for (int kk = 0; kk < 5; ++kk){
      __syncthreads();
      {
        int o = wave*1024 + lane*16;
        gl_lds16((const char*)Zt + ((size_t)kk*NNODE + m0)*128 + o,
                 (char*)Al + wave*1024);
      }
      #pragma unroll
      for (int i = 0; i < 8; ++i){
        int o = i*4096 + wave*1024 + lane*16;
        gl_lds16((const char*)T2w + (size_t)kk*32768 + o,
                 (char*)Bl + i*4096 + wave*1024);
      }
      __syncthreads();
      #pragma unroll
      for (int h = 0; h < 2; ++h){
        int ko = h*32 + q*8;
        s16x8 b[4];
        #pragma unroll
        for (int ni = 0; ni < 4; ++ni) b[ni] = *(const s16x8*)&Bl[(wave*64 + ni*16 + r)*64 + ko];
        #pragma unroll
        for (int mi = 0; mi < 2; ++mi){
          s16x8 a = *(const s16x8*)&Al[(mi*16 + r)*64 + ko];
          #pragma unroll
          for (int ni = 0; ni < 4; ++ni) acc[mi][ni] = mfma16(a, b[ni], acc[mi][ni]);
        }
      }
    }
    unsigned short* o8 = part + (size_t)8 * 2097152;
    #pragma unroll
    for (int mi = 0; mi < 2; ++mi)
      #pragma unroll
      for (int ni = 0; ni < 4; ++ni)
        #pragma unroll
        for (int ii = 0; ii < 4; ++ii){
          int m = m0 + mi*16 + q*4 + ii;
          int n = wave*64 + ni*16 + r;
          o8[(size_t)m*256 + n] = f2bf(acc[mi][ni][ii]);
        }
  }
}

// K11: H_half = H + sum(9 partial slabs); soft-threshold; -> Hprox bf16
__global__ __launch_bounds__(256) void k_combine(const float* __restrict__ H,
                                                 const unsigned short* __restrict__ part,
                                                 unsigned short* __restrict__ Hp){
  size_t e = ((size_t)blockIdx.x*256 + threadIdx.x)*4;
  f32x4 h = *(const f32x4*)(H + e);
  float s0 = h[0], s1 = h[1], s2 = h[2], s3 = h[3];
  #pragma unroll
  for (int sl = 0; sl < 9; ++sl){
    uint2 u = *(const uint2*)(part + (size_t)sl*2097152 + e);
    s0 += bf2f(u.x & 0xffff); s1 += bf2f(u.x >> 16);
    s2 += bf2f(u.y & 0xffff); s3 += bf2f(u.y >> 16);
  }
  #define PROX(a) ({ float _t = fabsf(a) - 0.025f; _t > 0.0f ? copysignf(_t,(a)) : 0.0f; })
  uint2 o;
  o.x = (unsigned)f2bf(PROX(s0)) | ((unsigned)f2bf(PROX(s1)) << 16);
  o.y = (unsigned)f2bf(PROX(s2)) | ((unsigned)f2bf(PROX(s3)) << 16);
  *(uint2*)(Hp + e) = o;
}

// ---------------------------------------------------------------------------
// K_FINLN: Hpre = Hprox @ W_in^T (bf16 MFMA) with fused LayerNorm epilogue.
// grid(128), BM=64 BN=256 K=256. Cross-wave row reduce via 2 KB LDS.
// ---------------------------------------------------------------------------
__global__ __launch_bounds__(256,2) void k_finln(const unsigned short* __restrict__ Hp,
                                                 const unsigned short* __restrict__ Wbf,
                                                 const float* __restrict__ gamma,
                                                 const float* __restrict__ beta,
                                                 float* __restrict__ out){
  __shared__ __align__(16) unsigned short Al[64][64];
  __shared__ __align__(16) unsigned short Bl[256][64];
  __shared__ float SmR[64][4];
  __shared__ float SqR[64][4];
  int tid = threadIdx.x, lane = tid & 63, wave = tid >> 6;
  int q = lane >> 4, r = lane & 15;
  int m0 = blockIdx.x * 64;
  f32x4 acc[4][4];
  #pragma unroll
  for (int a = 0; a < 4; ++a)
    #pragma unroll
    for (int b = 0; b < 4; ++b) acc[a][b] = (f32x4){0,0,0,0};
  for (int it = 0; it < 4; ++it){
    __syncthreads();
    #pragma unroll
    for (int i = 0; i < 2; ++i){
      int o = i*4096 + wave*1024 + lane*16;
      int row = o >> 7, kc = o & 127;
      gl_lds16((const char*)Hp + (size_t)(m0+row)*512 + it*128 + kc,
               (char*)&Al[0][0] + i*4096 + wave*1024);
    }
    #pragma unroll
    for (int i = 0; i < 8; ++i){
      int o = i*4096 + wave*1024 + lane*16;
      int n = o >> 7, kc = o & 127;
      gl_lds16((const char*)Wbf + (size_t)n*512 + it*128 + kc,
               (char*)&Bl[0][0] + i*4096 + wave*1024);
    }
    __syncthreads();
    #pragma unroll
    for (int h = 0; h < 2; ++h){
      int ko = h*32 + q*8;
      s16x8 b[4];
      #pragma unroll
      for (int ni = 0; ni < 4; ++ni) b[ni] = *(const s16x8*)&Bl[wave*64 + ni*16 + r][ko];
      #pragma unroll
      for (int mi = 0; mi < 4; ++mi){
        s16x8 a = *(const s16x8*)&Al[mi*16 + r][ko];
        #pragma unroll
        for (int ni = 0; ni < 4; ++ni) acc[mi][ni] = mfma16(a, b[ni], acc[mi][ni]);
      }
    }
  }
  // ---- LN epilogue ----
  // per lane: rows rl = mi*16 + q*4 + ii (16 of them); cols wave*64+ni*16+r.
  #pragma unroll
  for (int mi = 0; mi < 4; ++mi)
    #pragma unroll
    for (int ii = 0; ii < 4; ++ii){
      float sm = 0.0f, sq = 0.0f;
      #pragma unroll
      for (int ni = 0; ni < 4; ++ni){
        float v = acc[mi][ni][ii];
        sm += v; sq += v*v;
      }
      #pragma unroll
      for (int o = 1; o < 16; o <<= 1){ sm += __shfl_xor(sm, o, 64); sq += __shfl_xor(sq, o, 64); }
      if (r == 0){
        int rl = mi*16 + q*4 + ii;
        SmR[rl][wave] = sm; SqR[rl][wave] = sq;
      }
    }
  __syncthreads();
  float g[4], b[4];
  #pragma unroll
  for (int ni = 0; ni < 4; ++ni){
    g[ni] = gamma[wave*64 + ni*16 + r];
    b[ni] = beta [wave*64 + ni*16 + r];
  }
  #pragma unroll
  for (int mi = 0; mi < 4; ++mi)
    #pragma unroll
    for (int ii = 0; ii < 4; ++ii){
      int rl = mi*16 + q*4 + ii;
      float sm = SmR[rl][0] + SmR[rl][1] + SmR[rl][2] + SmR[rl][3];
      float sq = SqR[rl][0] + SqR[rl][1] + SqR[rl][2] + SqR[rl][3];
      float mean = sm * (1.0f/256.0f);
      float var  = sq * (1.0f/256.0f) - mean*mean;
      float rs   = rsqrtf(var + 1e-5f);
      #pragma unroll
      for (int ni = 0; ni < 4; ++ni){
        out[(size_t)(m0+rl)*256 + wave*64 + ni*16 + r] =
            (acc[mi][ni][ii] - mean)*rs*g[ni] + b[ni];
      }
    }
}

// ===========================================================================
extern "C" void kernel_launch(void* const* d_in, const int* in_sizes, int n_in,
                              void* d_out, int out_size, void* d_ws, size_t ws_size,
                              hipStream_t stream){
  const float* H    = (const float*)d_in[0];
  const float* hops = (const float*)d_in[1];
  const float* Lmat = (const float*)d_in[2];
  const float* U    = (const float*)d_in[3];
  const float* Win  = (const float*)d_in[4];
  const float* gam  = (const float*)d_in[5];
  const float* bet  = (const float*)d_in[6];
  const float* ltau = (const float*)d_in[7];
  float* out = (float*)d_out;

  char* ws = (char*)d_ws;
  float*          Qf   = (float*)(ws + OFF_Q);
  unsigned short* Qt   = (unsigned short*)(ws + OFF_QT);
  unsigned short* Zt   = (unsigned short*)(ws + OFF_ZT);
  float*          Gp   = (float*)(ws + OFF_GP);
  float*          Lm   = (float*)(ws + OFF_LM);
  float*          rdw  = (float*)(ws + OFF_RD);
  float*          Lu   = (float*)(ws + OFF_LU);
  float*          rdu  = (float*)(ws + OFF_RDU);
  float*          re   = (float*)(ws + OFF_RE);
  float*          wv   = (float*)(ws + OFF_W);
  unsigned short* T2w  = (unsigned short*)(ws + OFF_T2);
  unsigned short* hwT  = (unsigned short*)(ws + OFF_HWT);
  unsigned short* Wbf  = (unsigned short*)(ws + OFF_WBF);
  unsigned short* Hp   = (unsigned short*)(ws + OFF_HP);
  unsigned short* part = (unsigned short*)(ws + OFF_PART);
  unsigned short* Lbf  = (unsigned short*)(ws + OFF_LBF);

  hipLaunchKernelGGL(k_pre,    dim3(32773),  dim3(256), 0, stream, U, Lmat, Lu, rdu, Lbf);
  hipLaunchKernelGGL(k_qsolve, dim3(64,5),   dim3(256), 0, stream, U, Lu, rdu, Qf, Qt);
  hipLaunchKernelGGL(k_zgemm,  dim3(64,5),   dim3(256), 0, stream, hops, Qt, Zt);
  hipLaunchKernelGGL(k_gpart,  dim3(5,16),   dim3(256), 0, stream, Zt, Gp);
  hipLaunchKernelGGL(k_gred,   dim3(5),      dim3(256), 0, stream, Gp, Lm, rdw, re);
  hipLaunchKernelGGL(k_soft,   dim3(1),      dim3(64),  0, stream, re, ltau, wv, out + 2097152);
  hipLaunchKernelGGL(k_post,   dim3(896),    dim3(256), 0, stream, hops, wv, hwT, Qf, Lm, rdw, T2w, Win, Wbf);
  hipLaunchKernelGGL(k_gg,     dim3(768),    dim3(256), 0, stream, Lbf, hwT, part, Zt, T2w);
  hipLaunchKernelGGL(k_combine,dim3(2048),   dim3(256), 0, stream, H, part, Hp);
  hipLaunchKernelGGL(k_finln,  dim3(128),    dim3(256), 0, stream, Hp, Wbf, gam, bet, out);
}

// Round 3
// 628.084 us; speedup vs baseline: 1.1987x; 1.1987x over previous
//
#include <hip/hip_runtime.h>
#include <stdint.h>

// ============================================================================
// SubspaceRankHopLayer on MI355X (gfx950)
//
// R3: k_biggemm pure-DMA GEMM w/ chunk-padded LDS (verified 728.9 us).
// R5: fused 15 -> 10 launches. 753 us.
// R6 (this round): counters convicted k_pre (214 us, HBM 1.26 TB/s, VALU 2.9%,
// occ 33% time-avg): the 5-block LDS/barrier chol64 is a ~160 us serial tail
// with 251 CUs idle; k_gred has the same tail. Fix:
//   - wave-register Cholesky: 1 wave, lane=row, 64 VGPRs/lane, fully unrolled
//     rank-1 updates via __shfl broadcast. No barriers, no LDS. ~7 us.
//     Lower-triangle arithmetic identical; diag/upper never read downstream.
//   - stream role grid-strided: 2048 blocks x 16 iters (was 32768 one-shot).
// Predict 753 -> ~450 us; k_pre ~60 us.
// ============================================================================

typedef __attribute__((ext_vector_type(8))) short  s16x8;   // 8 bf16 (4 VGPR)
typedef __attribute__((ext_vector_type(4))) float  f32x4;

#define NNODE 8192
#define DIN   256
#define KHOP  5
#define SDM   64

// ---------------- ws layout (bytes) ----------------
static const size_t OFF_Q    = 0;                                   // Q f32 [5][256][64]
static const size_t OFF_QT   = OFF_Q   + (size_t)5*256*64*4;        // Qt bf16 [5][64][256]
static const size_t OFF_ZT   = OFF_QT  + (size_t)5*64*256*2;        // Zt bf16 [5][8192][64]
static const size_t OFF_GP   = OFF_ZT  + (size_t)5*8192*64*2;       // Gpart f32 [5][16][64][64]
static const size_t OFF_LM   = OFF_GP  + (size_t)5*16*4096*4;       // Lm f32 [5][64][64]
static const size_t OFF_RD   = OFF_LM  + (size_t)5*4096*4;          // rdiag f32 [5][64]
static const size_t OFF_LU   = OFF_RD  + (size_t)5*64*4;            // Lu f32 [5][64][64]
static const size_t OFF_RDU  = OFF_LU  + (size_t)5*4096*4;          // rdiag_u f32 [5][64]
static const size_t OFF_RE   = OFF_RDU + (size_t)5*64*4;            // rank_eff [5] (pad 64)
static const size_t OFF_W    = OFF_RE  + 64;                        // w [5] (pad 64)
static const size_t OFF_T2   = OFF_W   + 64;                        // T2w bf16 [5][256][64]
static const size_t OFF_HWT  = OFF_T2  + (size_t)5*256*64*2;        // hwT bf16 [256][8192]
static const size_t OFF_WBF  = OFF_HWT + (size_t)256*8192*2;        // W_in bf16 [256][256]
static const size_t OFF_HP   = OFF_WBF + (size_t)256*256*2;         // Hprox bf16 [8192][256]
static const size_t OFF_PART = OFF_HP  + (size_t)8192*256*2;        // partial bf16 [9][8192][256]
static const size_t OFF_LBF  = OFF_PART + (size_t)9*8192*256*2;     // L bf16 [8192][8192] (128 MB)

__device__ __forceinline__ unsigned short f2bf(float f){
  unsigned u = __builtin_bit_cast(unsigned, f);
  u += 0x7FFFu + ((u >> 16) & 1u);            // RNE
  return (unsigned short)(u >> 16);
}
__device__ __forceinline__ float bf2f(unsigned h){
  return __builtin_bit_cast(float, h << 16);
}
__device__ __forceinline__ void gl_lds16(const void* g, void* l){
  __builtin_amdgcn_global_load_lds(
      (const __attribute__((address_space(1))) void*)g,
      (__attribute__((address_space(3))) void*)l, 16, 0, 0);
}
__device__ __forceinline__ f32x4 mfma16(s16x8 a, s16x8 b, f32x4 c){
  return __builtin_amdgcn_mfma_f32_16x16x32_bf16(a, b, c, 0, 0, 0);
}

// ---------------------------------------------------------------------------
// Wave-register Cholesky of 64x64 SPD. One wave; lane = row; a[64] regs.
// Fully unrolled; broadcasts via __shfl (no LDS, no barriers).
// Lower-triangle arithmetic order identical to the old LDS chol64.
// Upper triangle accumulates garbage (never read downstream). rdk = 1/diag
// for this lane's row index.
// ---------------------------------------------------------------------------
__device__ __forceinline__ void wave_chol64(float* a, float& rdk, int lane){
  rdk = 0.0f;
  #pragma unroll
  for (int j = 0; j < 64; ++j){
    float dj  = __shfl(a[j], j);                 // A[j][j] fully updated
    float d   = sqrtf(fmaxf(dj, 1e-20f));
    float rdj = 1.0f / d;
    float cj  = a[j] * rdj;                      // L[i][j] (i>j); d at i==j
    a[j] = cj;
    if (lane == j) rdk = rdj;
    #pragma unroll
    for (int l = j+1; l < 64; ++l)
      a[l] -= cj * __shfl(cj, l);                // rank-1 update, col l
  }
}

// ---------------------------------------------------------------------------
// K_PRE: blocks 0-4: Gram (256 thr) + wave0 register-Cholesky of U_k.
//        blocks 5..2052: L f32 -> bf16 grid-stride stream (16 iters).
// ---------------------------------------------------------------------------
__global__ __launch_bounds__(256) void k_pre(const float* __restrict__ U,
                                             const float* __restrict__ L,
                                             float* __restrict__ Lu,
                                             float* __restrict__ rdu,
                                             unsigned short* __restrict__ Lbf){
  __shared__ float A[64*65];
  int tid = threadIdx.x;
  if (blockIdx.x >= 5){
    size_t base = (size_t)(blockIdx.x - 5);
    #pragma unroll 4
    for (int it = 0; it < 16; ++it){
      size_t e = ((base + (size_t)it*2048)*256 + tid)*8;
      f32x4 a = *(const f32x4*)(L + e);
      f32x4 b = *(const f32x4*)(L + e + 4);
      uint4 u;
      u.x = (unsigned)f2bf(a[0]) | ((unsigned)f2bf(a[1]) << 16);
      u.y = (unsigned)f2bf(a[2]) | ((unsigned)f2bf(a[3]) << 16);
      u.z = (unsigned)f2bf(b[0]) | ((unsigned)f2bf(b[1]) << 16);
      u.w = (unsigned)f2bf(b[2]) | ((unsigned)f2bf(b[3]) << 16);
      *(uint4*)(Lbf + e) = u;
    }
    return;
  }
  int k = blockIdx.x;
  const float* Uk = U + (size_t)k*16384;
  int ti = tid >> 4, tj = tid & 15;
  float s[16];
  #pragma unroll
  for (int i = 0; i < 16; ++i) s[i] = 0.0f;
  for (int n = 0; n < 256; ++n){
    f32x4 xa = *(const f32x4*)(Uk + n*64 + ti*4);
    f32x4 xb = *(const f32x4*)(Uk + n*64 + tj*4);
    #pragma unroll
    for (int p = 0; p < 4; ++p)
      #pragma unroll
      for (int q = 0; q < 4; ++q) s[p*4+q] += xa[p]*xb[q];
  }
  #pragma unroll
  for (int p = 0; p < 4; ++p)
    #pragma unroll
    for (int q = 0; q < 4; ++q) A[(ti*4+p)*65 + tj*4+q] = s[p*4+q];
  __syncthreads();
  if (tid < 64){
    int lane = tid;
    float a[64];
    #pragma unroll
    for (int l = 0; l < 64; ++l) a[l] = A[lane*65 + l];
    float rdk;
    wave_chol64(a, rdk, lane);
    #pragma unroll
    for (int l = 0; l < 64; ++l) Lu[(size_t)k*4096 + lane*64 + l] = a[l];
    rdu[k*64 + lane] = rdk;
  }
}

// ---------------------------------------------------------------------------
// K1b: wave-parallel forward solve L x = u_row -> Q rows. grid(64,5).
// ---------------------------------------------------------------------------
__global__ __launch_bounds__(256) void k_qsolve(const float* __restrict__ U,
                                                const float* __restrict__ Lu,
                                                const float* __restrict__ rdu,
                                                float* __restrict__ Qf,
                                                unsigned short* __restrict__ Qt){
  int k = blockIdx.y, tid = threadIdx.x, wave = tid >> 6, lane = tid & 63;
  __shared__ float Al[64*65];
  __shared__ float rds[64];
  for (int e = tid; e < 4096; e += 256) Al[(e>>6)*65 + (e&63)] = Lu[(size_t)k*4096 + e];
  if (tid < 64) rds[tid] = rdu[k*64 + tid];
  __syncthreads();
  int n = blockIdx.x*4 + wave;
  float x = U[((size_t)k*256 + n)*64 + lane];
  #pragma unroll
  for (int j = 0; j < 64; ++j){
    float zj = __shfl(x, j) * rds[j];
    x = (lane == j) ? zj : (lane > j ? x - Al[lane*65+j]*zj : x);
  }
  Qf[((size_t)k*256 + n)*64 + lane] = x;
  Qt[(size_t)k*16384 + lane*256 + n] = f2bf(x);   // Qt[k][s][d]
}

// ---------------------------------------------------------------------------
// K2: Z_k = hops_k @ Q_k  [8192,64] bf16.  grid(64,5), BM=128 BN=64 BK=64.
// ---------------------------------------------------------------------------
__global__ __launch_bounds__(256,2) void k_zgemm(const float* __restrict__ hops,
                                                 const unsigned short* __restrict__ Qt,
                                                 unsigned short* __restrict__ Zt){
  __shared__ __align__(16) unsigned short Al[128][72];
  __shared__ __align__(16) unsigned short Bl[64][64];
  int tid = threadIdx.x, lane = tid & 63, wave = tid >> 6;
  int q = lane >> 4, r = lane & 15;
  int k = blockIdx.y, m0 = blockIdx.x * 128;
  f32x4 acc[2][4];
  #pragma unroll
  for (int a = 0; a < 2; ++a)
    #pragma unroll
    for (int b = 0; b < 4; ++b) acc[a][b] = (f32x4){0,0,0,0};
  int rr = tid >> 1, half = tid & 1;
  for (int it = 0; it < 4; ++it){
    __syncthreads();
    #pragma unroll
    for (int i = 0; i < 2; ++i){
      int o = i*4096 + wave*1024 + lane*16;
      int srow = o >> 7, kc = (o & 127) >> 1;
      gl_lds16(Qt + (size_t)k*16384 + srow*256 + it*64 + kc,
               (char*)&Bl[0][0] + i*4096 + wave*1024);
    }
    const float* ga = hops + ((size_t)k*NNODE + m0 + rr)*256 + it*64 + half*32;
    f32x4 v[8];
    #pragma unroll
    for (int i = 0; i < 8; ++i) v[i] = *(const f32x4*)(ga + i*4);
    #pragma unroll
    for (int i = 0; i < 4; ++i){
      s16x8 t;
      #pragma unroll
      for (int j = 0; j < 8; ++j){ int e = i*8+j; t[j] = (short)f2bf(v[e>>2][e&3]); }
      *(s16x8*)&Al[rr][half*32 + i*8] = t;
    }
    __syncthreads();
    #pragma unroll
    for (int h = 0; h < 2; ++h){
      int ko = h*32 + q*8;
      s16x8 b[4];
      #pragma unroll
      for (int ni = 0; ni < 4; ++ni) b[ni] = *(const s16x8*)&Bl[ni*16 + r][ko];
      #pragma unroll
      for (int mi = 0; mi < 2; ++mi){
        s16x8 a = *(const s16x8*)&Al[wave*32 + mi*16 + r][ko];
        #pragma unroll
        for (int ni = 0; ni < 4; ++ni) acc[mi][ni] = mfma16(a, b[ni], acc[mi][ni]);
      }
    }
  }
  #pragma unroll
  for (int mi = 0; mi < 2; ++mi)
    #pragma unroll
    for (int ni = 0; ni < 4; ++ni)
      #pragma unroll
      for (int ii = 0; ii < 4; ++ii){
        int m = m0 + wave*32 + mi*16 + q*4 + ii;
        int sc = ni*16 + r;
        Zt[((size_t)k*NNODE + m)*64 + sc] = f2bf(acc[mi][ni][ii]);
      }
}

// ---------------------------------------------------------------------------
// K3: partial Gram over 512-row chunks. grid(5,16).
// ---------------------------------------------------------------------------
__global__ __launch_bounds__(256) void k_gpart(const unsigned short* __restrict__ Zt,
                                               float* __restrict__ Gp){
  int k = blockIdx.x, c = blockIdx.y, tid = threadIdx.x;
  __shared__ __align__(16) unsigned short Zl[128][64];
  int ti = tid >> 4, tj = tid & 15;
  float acc[16];
  #pragma unroll
  for (int i = 0; i < 16; ++i) acc[i] = 0.0f;
  for (int sub = 0; sub < 4; ++sub){
    const char* gb = (const char*)Zt + ((size_t)k*NNODE + c*512 + sub*128)*128;
    __syncthreads();
    #pragma unroll
    for (int i = 0; i < 4; ++i){
      int o = i*4096 + tid*16;
      *(uint4*)((char*)&Zl[0][0] + o) = *(const uint4*)(gb + o);
    }
    __syncthreads();
    for (int n = 0; n < 128; ++n){
      const unsigned short* row = &Zl[n][0];
      uint2 ua = *(const uint2*)(row + ti*4);
      uint2 ub = *(const uint2*)(row + tj*4);
      float xa[4] = { bf2f(ua.x & 0xffff), bf2f(ua.x >> 16), bf2f(ua.y & 0xffff), bf2f(ua.y >> 16) };
      float xb[4] = { bf2f(ub.x & 0xffff), bf2f(ub.x >> 16), bf2f(ub.y & 0xffff), bf2f(ub.y >> 16) };
      #pragma unroll
      for (int p = 0; p < 4; ++p)
        #pragma unroll
        for (int qn = 0; qn < 4; ++qn) acc[p*4+qn] += xa[p]*xb[qn];
    }
  }
  float* o = Gp + ((size_t)k*16 + c)*4096;
  #pragma unroll
  for (int p = 0; p < 4; ++p)
    #pragma unroll
    for (int qn = 0; qn < 4; ++qn) o[(ti*4+p)*64 + tj*4+qn] = acc[p*4+qn];
}

// ---------------------------------------------------------------------------
// K4: reduce Gpart -> G; rank_eff; M = I + coeff*G; wave0 register-chol(M).
// 5 blocks.
// ---------------------------------------------------------------------------
__global__ __launch_bounds__(256) void k_gred(const float* __restrict__ Gp,
                                              float* __restrict__ LmO,
                                              float* __restrict__ rdO,
                                              float* __restrict__ reO){
  int k = blockIdx.x, tid = threadIdx.x;
  __shared__ float A[64*65];
  __shared__ float red[256];
  int ti = tid >> 4, tj = tid & 15;
  float s[16];
  #pragma unroll
  for (int i = 0; i < 16; ++i) s[i] = 0.0f;
  for (int c = 0; c < 16; ++c){
    const float* g = Gp + ((size_t)k*16 + c)*4096 + (ti*4)*64 + tj*4;
    #pragma unroll
    for (int p = 0; p < 4; ++p)
      #pragma unroll
      for (int qn = 0; qn < 4; ++qn) s[p*4+qn] += g[p*64+qn];
  }
  const float sc    = 1.0f / (8192.0f + 1e-8f);
  const float coeff = 64.0f / (8192.0f*0.25f + 1e-8f);
  float trp = 0.0f, tr2p = 0.0f;
  #pragma unroll
  for (int p = 0; p < 4; ++p)
    #pragma unroll
    for (int qn = 0; qn < 4; ++qn){
      float gg = s[p*4+qn];
      float sg = gg * sc;
      tr2p += sg*sg;
      int row = ti*4+p, col = tj*4+qn;
      if (row == col) trp += sg;
      A[row*65 + col] = (row == col ? 1.0f : 0.0f) + coeff*gg;
    }
  red[tid] = trp; __syncthreads();
  for (int o = 128; o > 0; o >>= 1){ if (tid < o) red[tid] += red[tid+o]; __syncthreads(); }
  float tr = red[0]; __syncthreads();
  red[tid] = tr2p; __syncthreads();
  for (int o = 128; o > 0; o >>= 1){ if (tid < o) red[tid] += red[tid+o]; __syncthreads(); }
  float tr2 = red[0];
  if (tid == 0) reO[k] = tr*tr / (tr2 + 1e-8f);
  __syncthreads();
  if (tid < 64){
    int lane = tid;
    float a[64];
    #pragma unroll
    for (int l = 0; l < 64; ++l) a[l] = A[lane*65 + l];
    float rdk;
    wave_chol64(a, rdk, lane);
    #pragma unroll
    for (int l = 0; l < 64; ++l) LmO[(size_t)k*4096 + lane*64 + l] = a[l];
    rdO[k*64 + lane] = rdk;
  }
}

// ---------------------------------------------------------------------------
// K5: tau, softmax over rank_effs -> w; write output tail. 1 block.
// ---------------------------------------------------------------------------
__global__ void k_soft(const float* __restrict__ re, const float* __restrict__ ltau,
                       float* __restrict__ wv, float* __restrict__ dtail){
  if (threadIdx.x == 0){
    float tau = expf(ltau[0]);
    tau = fminf(fmaxf(tau, 0.1f), 10.0f);
    float r[5], m = -1e30f;
    for (int i = 0; i < 5; ++i){ r[i] = re[i]; m = fmaxf(m, r[i]); }
    float e[5], sum = 0.0f;
    for (int i = 0; i < 5; ++i){ e[i] = expf((r[i]-m)/tau); sum += e[i]; }
    for (int i = 0; i < 5; ++i){
      float w = e[i]/sum;
      wv[i] = w; dtail[i] = r[i]; dtail[5+i] = w;
    }
  }
}

// ---------------------------------------------------------------------------
// K_POST: horizontal fusion, 896 blocks:
//   [0,512):   hwT role  (x = i&127 -> n0, y = i>>7 -> d0)
//   [512,832): t2w role  (i-512: k = i>>6, xb = i&63)
//   [832,896): wbf role
// ---------------------------------------------------------------------------
__global__ __launch_bounds__(256) void k_post(const float* __restrict__ hops,
                                              const float* __restrict__ wv,
                                              unsigned short* __restrict__ hwT,
                                              const float* __restrict__ Qf,
                                              const float* __restrict__ LmI,
                                              const float* __restrict__ rdI,
                                              unsigned short* __restrict__ T2w,
                                              const float* __restrict__ Win,
                                              unsigned short* __restrict__ Wbf){
  __shared__ float T[64*65];
  __shared__ float rds[64];
  int bid = blockIdx.x, tid = threadIdx.x;
  if (bid < 512){
    // ---- hwT role ----
    int n0 = (bid & 127)*64, d0 = (bid >> 7)*64;
    float wl[5];
    #pragma unroll
    for (int k = 0; k < 5; ++k) wl[k] = -0.15f * wv[k];   // -ETA*LAM_LAP*w_k
    for (int e = tid; e < 1024; e += 256){
      int row = e >> 4, c4 = (e & 15)*4;
      f32x4 acc = (f32x4){0,0,0,0};
      #pragma unroll
      for (int k = 0; k < 5; ++k){
        f32x4 v = *(const f32x4*)(hops + ((size_t)k*NNODE + n0 + row)*256 + d0 + c4);
        acc += v * wl[k];
      }
      T[row*65 + c4+0] = acc[0]; T[row*65 + c4+1] = acc[1];
      T[row*65 + c4+2] = acc[2]; T[row*65 + c4+3] = acc[3];
    }
    __syncthreads();
    for (int e = tid; e < 1024; e += 256){
      int dr = e >> 4, c4 = (e & 15)*4;
      unsigned short h0 = f2bf(T[(c4+0)*65 + dr]);
      unsigned short h1 = f2bf(T[(c4+1)*65 + dr]);
      unsigned short h2 = f2bf(T[(c4+2)*65 + dr]);
      unsigned short h3 = f2bf(T[(c4+3)*65 + dr]);
      uint2 u; u.x = (unsigned)h0 | ((unsigned)h1 << 16); u.y = (unsigned)h2 | ((unsigned)h3 << 16);
      *(uint2*)(hwT + (size_t)(d0+dr)*NNODE + n0 + c4) = u;
    }
  } else if (bid < 832){
    // ---- t2w role: fwd+bwd solve, T2w = ETA*w_k*(M^-1 Q^T) ----
    int i = bid - 512;
    int k = i >> 6, xb = i & 63;
    int wave = tid >> 6, lane = tid & 63;
    for (int e = tid; e < 4096; e += 256) T[(e>>6)*65 + (e&63)] = LmI[(size_t)k*4096 + e];
    if (tid < 64) rds[tid] = rdI[k*64 + tid];
    __syncthreads();
    int n = xb*4 + wave;
    float x = Qf[((size_t)k*256 + n)*64 + lane];
    #pragma unroll
    for (int j = 0; j < 64; ++j){                 // forward: L z = q
      float zj = __shfl(x, j) * rds[j];
      x = (lane == j) ? zj : (lane > j ? x - T[lane*65+j]*zj : x);
    }
    #pragma unroll
    for (int j = 63; j >= 0; --j){                // backward: L^T y = z
      float yj = __shfl(x, j) * rds[j];
      x = (lane == j) ? yj : (lane < j ? x - T[j*65+lane]*yj : x);
    }
    float scale = 0.5f * wv[k];                   // ETA * w_k
    T2w[((size_t)k*256 + n)*64 + lane] = f2bf(scale * x);
  } else {
    // ---- wbf role ----
    int i = bid - 832;
    int e = (i*256 + tid)*4;
    f32x4 v = *(const f32x4*)(Win + e);
    uint2 u;
    u.x = (unsigned)f2bf(v[0]) | ((unsigned)f2bf(v[1]) << 16);
    u.y = (unsigned)f2bf(v[2]) | ((unsigned)f2bf(v[3]) << 16);
    *(uint2*)(Wbf + e) = u;
  }
}

// ---------------------------------------------------------------------------
// K_GG: horizontal fusion, 768 blocks, shared 49.9 KB LDS arena:
//   [0,512):   biggemm role (bx = i&63, by = i>>6), chunk-padded pure-DMA
//   [512,768): gradgemm role (m0 = (i-512)*32)
// ---------------------------------------------------------------------------
__global__ __launch_bounds__(256,2) void k_gg(const unsigned short* __restrict__ Lbf,
                                              const unsigned short* __restrict__ Bt,
                                              unsigned short* __restrict__ part,
                                              const unsigned short* __restrict__ Zt,
                                              const unsigned short* __restrict__ T2w){
  __shared__ __align__(16) unsigned short SM[24960];   // 49,920 B arena
  int bid = blockIdx.x, tid = threadIdx.x;
  int lane = tid & 63, wave = tid >> 6;
  int q = lane >> 4, r = lane & 15;
  if (bid < 512){
    // ---- biggemm role ----
    unsigned short* Al = SM;            // 16 chunks x 1040 B
    unsigned short* Bl = SM + 16*520;   // 32 chunks x 1040 B
    int m0 = (bid & 63) * 128;
    int by = bid >> 6;
    size_t kbase = (size_t)by * 1024;
    int sr = lane >> 3, sc8 = (lane & 7) * 8;
    f32x4 acc[8][4];
    #pragma unroll
    for (int a = 0; a < 8; ++a)
      #pragma unroll
      for (int b = 0; b < 4; ++b) acc[a][b] = (f32x4){0,0,0,0};
    for (int it = 0; it < 16; ++it){
      size_t k0 = kbase + it*64;
      __syncthreads();
      #pragma unroll
      for (int i = 0; i < 12; ++i){             // 48 chunks: 16 A + 32 B
        int c = i*4 + wave;                     // wave-uniform
        if (c < 16){
          gl_lds16(Lbf + (size_t)(m0 + c*8 + sr)*NNODE + k0 + sc8,
                   (char*)Al + c*1040 + lane*16);
        } else {
          int cb = c - 16;
          gl_lds16(Bt + (size_t)(cb*8 + sr)*NNODE + k0 + sc8,
                   (char*)Bl + cb*1040 + lane*16);
        }
      }
      __syncthreads();
      #pragma unroll
      for (int h = 0; h < 2; ++h){
        int ko = h*32 + q*8;
        s16x8 b[4];
        #pragma unroll
        for (int ni = 0; ni < 4; ++ni){
          int d = wave*64 + ni*16 + r;
          b[ni] = *(const s16x8*)(Bl + (d>>3)*520 + (d&7)*64 + ko);
        }
        #pragma unroll
        for (int mi = 0; mi < 8; ++mi){
          int m = mi*16 + r;
          s16x8 a = *(const s16x8*)(Al + (m>>3)*520 + (m&7)*64 + ko);
          #pragma unroll
          for (int ni = 0; ni < 4; ++ni) acc[mi][ni] = mfma16(a, b[ni], acc[mi][ni]);
        }
      }
    }
    unsigned short* o = part + (size_t)by * 2097152;
    #pragma unroll
    for (int mi = 0; mi < 8; ++mi)
      #pragma unroll
      for (int ni = 0; ni < 4; ++ni)
        #pragma unroll
        for (int ii = 0; ii < 4; ++ii){
          int m = m0 + mi*16 + q*4 + ii;
          int n = wave*64 + ni*16 + r;
          o[(size_t)m*256 + n] = f2bf(acc[mi][ni][ii]);
        }
  } else {
    // ---- gradgemm role: Zstack[8192,320] @ T2w-stack[320,256] -> slab 8 ----
    unsigned short* Al = SM;            // 32 x 64
    unsigned short* Bl = SM + 2048;     // 256 x 64
    int m0 = (bid - 512) * 32;
    f32x4 acc[2][4];
    #pragma unroll
    for (int a = 0; a < 2; ++a)
      #pragma unroll
      for (int b = 0; b < 4; ++b) acc[a][b] = (f32x4){0,0,0,0};
    for (int kk = 0; kk < 5; ++kk){
      __syncthreads();
      {
        int o = wave*1024 + lane*16;
        gl_lds16((const char*)Zt + ((size_t)kk*NNODE + m0)*128 + o,
                 (char*)Al + wave*1024);
      }
      #pragma unroll
      for (int i = 0; i < 8; ++i){
        int o = i*4096 + wave*1024 + lane*16;
        gl_lds16((const char*)T2w + (size_t)kk*32768 + o,
                 (char*)Bl + i*4096 + wave*1024);
      }
      __syncthreads();
      #pragma unroll
      for (int h = 0; h < 2; ++h){
        int ko = h*32 + q*8;
        s16x8 b[4];
        #pragma unroll
        for (int ni = 0; ni < 4; ++ni) b[ni] = *(const s16x8*)&Bl[(wave*64 + ni*16 + r)*64 + ko];
        #pragma unroll
        for (int mi = 0; mi < 2; ++mi){
          s16x8 a = *(const s16x8*)&Al[(mi*16 + r)*64 + ko];
          #pragma unroll
          for (int ni = 0; ni < 4; ++ni) acc[mi][ni] = mfma16(a, b[ni], acc[mi][ni]);
        }
      }
    }
    unsigned short* o8 = part + (size_t)8 * 2097152;
    #pragma unroll
    for (int mi = 0; mi < 2; ++mi)
      #pragma unroll
      for (int ni = 0; ni < 4; ++ni)
        #pragma unroll
        for (int ii = 0; ii < 4; ++ii){
          int m = m0 + mi*16 + q*4 + ii;
          int n = wave*64 + ni*16 + r;
          o8[(size_t)m*256 + n] = f2bf(acc[mi][ni][ii]);
        }
  }
}

// K11: H_half = H + sum(9 partial slabs); soft-threshold; -> Hprox bf16
__global__ __launch_bounds__(256) void k_combine(const float* __restrict__ H,
                                                 const unsigned short* __restrict__ part,
                                                 unsigned short* __restrict__ Hp){
  size_t e = ((size_t)blockIdx.x*256 + threadIdx.x)*4;
  f32x4 h = *(const f32x4*)(H + e);
  float s0 = h[0], s1 = h[1], s2 = h[2], s3 = h[3];
  #pragma unroll
  for (int sl = 0; sl < 9; ++sl){
    uint2 u = *(const uint2*)(part + (size_t)sl*2097152 + e);
    s0 += bf2f(u.x & 0xffff); s1 += bf2f(u.x >> 16);
    s2 += bf2f(u.y & 0xffff); s3 += bf2f(u.y >> 16);
  }
  #define PROX(a) ({ float _t = fabsf(a) - 0.025f; _t > 0.0f ? copysignf(_t,(a)) : 0.0f; })
  uint2 o;
  o.x = (unsigned)f2bf(PROX(s0)) | ((unsigned)f2bf(PROX(s1)) << 16);
  o.y = (unsigned)f2bf(PROX(s2)) | ((unsigned)f2bf(PROX(s3)) << 16);
  *(uint2*)(Hp + e) = o;
}

// ---------------------------------------------------------------------------
// K_FINLN: Hpre = Hprox @ W_in^T (bf16 MFMA) with fused LayerNorm epilogue.
// grid(128), BM=64 BN=256 K=256. Cross-wave row reduce via 2 KB LDS.
// ---------------------------------------------------------------------------
__global__ __launch_bounds__(256,2) void k_finln(const unsigned short* __restrict__ Hp,
                                                 const unsigned short* __restrict__ Wbf,
                                                 const float* __restrict__ gamma,
                                                 const float* __restrict__ beta,
                                                 float* __restrict__ out){
  __shared__ __align__(16) unsigned short Al[64][64];
  __shared__ __align__(16) unsigned short Bl[256][64];
  __shared__ float SmR[64][4];
  __shared__ float SqR[64][4];
  int tid = threadIdx.x, lane = tid & 63, wave = tid >> 6;
  int q = lane >> 4, r = lane & 15;
  int m0 = blockIdx.x * 64;
  f32x4 acc[4][4];
  #pragma unroll
  for (int a = 0; a < 4; ++a)
    #pragma unroll
    for (int b = 0; b < 4; ++b) acc[a][b] = (f32x4){0,0,0,0};
  for (int it = 0; it < 4; ++it){
    __syncthreads();
    #pragma unroll
    for (int i = 0; i < 2; ++i){
      int o = i*4096 + wave*1024 + lane*16;
      int row = o >> 7, kc = o & 127;
      gl_lds16((const char*)Hp + (size_t)(m0+row)*512 + it*128 + kc,
               (char*)&Al[0][0] + i*4096 + wave*1024);
    }
    #pragma unroll
    for (int i = 0; i < 8; ++i){
      int o = i*4096 + wave*1024 + lane*16;
      int n = o >> 7, kc = o & 127;
      gl_lds16((const char*)Wbf + (size_t)n*512 + it*128 + kc,
               (char*)&Bl[0][0] + i*4096 + wave*1024);
    }
    __syncthreads();
    #pragma unroll
    for (int h = 0; h < 2; ++h){
      int ko = h*32 + q*8;
      s16x8 b[4];
      #pragma unroll
      for (int ni = 0; ni < 4; ++ni) b[ni] = *(const s16x8*)&Bl[wave*64 + ni*16 + r][ko];
      #pragma unroll
      for (int mi = 0; mi < 4; ++mi){
        s16x8 a = *(const s16x8*)&Al[mi*16 + r][ko];
        #pragma unroll
        for (int ni = 0; ni < 4; ++ni) acc[mi][ni] = mfma16(a, b[ni], acc[mi][ni]);
      }
    }
  }
  // ---- LN epilogue ----
  #pragma unroll
  for (int mi = 0; mi < 4; ++mi)
    #pragma unroll
    for (int ii = 0; ii < 4; ++ii){
      float sm = 0.0f, sq = 0.0f;
      #pragma unroll
      for (int ni = 0; ni < 4; ++ni){
        float v = acc[mi][ni][ii];
        sm += v; sq += v*v;
      }
      #pragma unroll
      for (int o = 1; o < 16; o <<= 1){ sm += __shfl_xor(sm, o, 64); sq += __shfl_xor(sq, o, 64); }
      if (r == 0){
        int rl = mi*16 + q*4 + ii;
        SmR[rl][wave] = sm; SqR[rl][wave] = sq;
      }
    }
  __syncthreads();
  float g[4], b[4];
  #pragma unroll
  for (int ni = 0; ni < 4; ++ni){
    g[ni] = gamma[wave*64 + ni*16 + r];
    b[ni] = beta [wave*64 + ni*16 + r];
  }
  #pragma unroll
  for (int mi = 0; mi < 4; ++mi)
    #pragma unroll
    for (int ii = 0; ii < 4; ++ii){
      int rl = mi*16 + q*4 + ii;
      float sm = SmR[rl][0] + SmR[rl][1] + SmR[rl][2] + SmR[rl][3];
      float sq = SqR[rl][0] + SqR[rl][1] + SqR[rl][2] + SqR[rl][3];
      float mean = sm * (1.0f/256.0f);
      float var  = sq * (1.0f/256.0f) - mean*mean;
      float rs   = rsqrtf(var + 1e-5f);
      #pragma unroll
      for (int ni = 0; ni < 4; ++ni){
        out[(size_t)(m0+rl)*256 + wave*64 + ni*16 + r] =
            (acc[mi][ni][ii] - mean)*rs*g[ni] + b[ni];
      }
    }
}

// ===========================================================================
extern "C" void kernel_launch(void* const* d_in, const int* in_sizes, int n_in,
                              void* d_out, int out_size, void* d_ws, size_t ws_size,
                              hipStream_t stream){
  const float* H    = (const float*)d_in[0];
  const float* hops = (const float*)d_in[1];
  const float* Lmat = (const float*)d_in[2];
  const float* U    = (const float*)d_in[3];
  const float* Win  = (const float*)d_in[4];
  const float* gam  = (const float*)d_in[5];
  const float* bet  = (const float*)d_in[6];
  const float* ltau = (const float*)d_in[7];
  float* out = (float*)d_out;

  char* ws = (char*)d_ws;
  float*          Qf   = (float*)(ws + OFF_Q);
  unsigned short* Qt   = (unsigned short*)(ws + OFF_QT);
  unsigned short* Zt   = (unsigned short*)(ws + OFF_ZT);
  float*          Gp   = (float*)(ws + OFF_GP);
  float*          Lm   = (float*)(ws + OFF_LM);
  float*          rdw  = (float*)(ws + OFF_RD);
  float*          Lu   = (float*)(ws + OFF_LU);
  float*          rdu  = (float*)(ws + OFF_RDU);
  float*          re   = (float*)(ws + OFF_RE);
  float*          wv   = (float*)(ws + OFF_W);
  unsigned short* T2w  = (unsigned short*)(ws + OFF_T2);
  unsigned short* hwT  = (unsigned short*)(ws + OFF_HWT);
  unsigned short* Wbf  = (unsigned short*)(ws + OFF_WBF);
  unsigned short* Hp   = (unsigned short*)(ws + OFF_HP);
  unsigned short* part = (unsigned short*)(ws + OFF_PART);
  unsigned short* Lbf  = (unsigned short*)(ws + OFF_LBF);

  hipLaunchKernelGGL(k_pre,    dim3(2053),   dim3(256), 0, stream, U, Lmat, Lu, rdu, Lbf);
  hipLaunchKernelGGL(k_qsolve, dim3(64,5),   dim3(256), 0, stream, U, Lu, rdu, Qf, Qt);
  hipLaunchKernelGGL(k_zgemm,  dim3(64,5),   dim3(256), 0, stream, hops, Qt, Zt);
  hipLaunchKernelGGL(k_gpart,  dim3(5,16),   dim3(256), 0, stream, Zt, Gp);
  hipLaunchKernelGGL(k_gred,   dim3(5),      dim3(256), 0, stream, Gp, Lm, rdw, re);
  hipLaunchKernelGGL(k_soft,   dim3(1),      dim3(64),  0, stream, re, ltau, wv, out + 2097152);
  hipLaunchKernelGGL(k_post,   dim3(896),    dim3(256), 0, stream, hops, wv, hwT, Qf, Lm, rdw, T2w, Win, Wbf);
  hipLaunchKernelGGL(k_gg,     dim3(768),    dim3(256), 0, stream, Lbf, hwT, part, Zt, T2w);
  hipLaunchKernelGGL(k_combine,dim3(2048),   dim3(256), 0, stream, H, part, Hp);
  hipLaunchKernelGGL(k_finln,  dim3(128),    dim3(256), 0, stream, Hp, Wbf, gam, bet, out);
}